// Round 1
// baseline (756.845 us; speedup 1.0000x reference)
//
#include <hip/hip_runtime.h>
#include <stdint.h>

static constexpr int Bn = 16, Tn = 2048, En = 1024, NHn = 16, HDn = 64, NLEVn = 12;

typedef __attribute__((ext_vector_type(8))) short short8;
typedef __attribute__((ext_vector_type(4))) float floatx4;

__device__ __forceinline__ unsigned short f2bf(float f) {
  unsigned int u = __float_as_uint(f);
  u += 0x7fffu + ((u >> 16) & 1u);
  return (unsigned short)(u >> 16);
}
__device__ __forceinline__ float bf2f(unsigned short s) {
  return __uint_as_float(((unsigned int)s) << 16);
}

__device__ __forceinline__ void async16(const unsigned short* g, unsigned short* l) {
  __builtin_amdgcn_global_load_lds(
      (const __attribute__((address_space(1))) unsigned int*)g,
      (__attribute__((address_space(3))) unsigned int*)l, 16, 0, 0);
}

// ---------------- fp32 -> bf16 convert ----------------
__global__ void k_cvt(const float* __restrict__ in, unsigned short* __restrict__ out, int n4) {
  int i = blockIdx.x * 256 + threadIdx.x;
  if (i < n4) {
    float4 v = ((const float4*)in)[i];
    ushort4 o;
    o.x = f2bf(v.x); o.y = f2bf(v.y); o.z = f2bf(v.z); o.w = f2bf(v.w);
    ((ushort4*)out)[i] = o;
  }
}

// ---------------- per-head prefix scan of log(sigmoid(A)) ----------------
__global__ void k_scan(const float* __restrict__ A_log, const float* __restrict__ A_bias,
                       float* __restrict__ cs) {
  int h = blockIdx.x;       // NH blocks
  int tid = threadIdx.x;    // 256 threads, 8 t each
  __shared__ float part[256];
  float loc[8];
  float run = 0.f;
#pragma unroll
  for (int j = 0; j < 8; j++) {
    int t = tid * 8 + j;
    float x = A_log[t * NHn + h] + A_bias[t * NHn + h];
    float ls = -log1pf(__expf(-x));   // log(sigmoid(x))
    run += ls;
    loc[j] = run;
  }
  part[tid] = run;
  __syncthreads();
  for (int d = 1; d < 256; d <<= 1) {
    float v = (tid >= d) ? part[tid - d] : 0.f;
    __syncthreads();
    part[tid] += v;
    __syncthreads();
  }
  float off = (tid > 0) ? part[tid - 1] : 0.f;
#pragma unroll
  for (int j = 0; j < 8; j++) cs[(tid * 8 + j) * NHn + h] = loc[j] + off;
}

// ---------------- unnormalized weights P[h][t][s] (bf16) + row sums ----------------
__global__ void k_weights(const float* __restrict__ L, const float* __restrict__ Lb,
                          const int* __restrict__ levels, const float* __restrict__ cs,
                          unsigned short* __restrict__ P, float* __restrict__ denom) {
  int t = blockIdx.x;       // T blocks
  int tid = threadIdx.x;    // 256
  __shared__ float Lrow[NHn * NLEVn];
  __shared__ float cst[NHn];
  __shared__ float dsum[NHn];
  if (tid < NHn * NLEVn) Lrow[tid] = L[t * NHn * NLEVn + tid] + Lb[t * NHn * NLEVn + tid];
  if (tid < NHn) { cst[tid] = cs[t * NHn + tid]; dsum[tid] = 0.f; }
  __syncthreads();
  float acc[NHn];
#pragma unroll
  for (int h = 0; h < NHn; h++) acc[h] = 0.f;
  for (int s = tid; s < Tn; s += 256) {
    int lev = levels[(size_t)t * Tn + s];
    bool causal = (s <= t);
    float csr[NHn];
    const float4* c4 = (const float4*)(cs + s * NHn);
#pragma unroll
    for (int q = 0; q < 4; q++) {
      float4 v = c4[q];
      csr[q * 4 + 0] = v.x; csr[q * 4 + 1] = v.y; csr[q * 4 + 2] = v.z; csr[q * 4 + 3] = v.w;
    }
#pragma unroll
    for (int h = 0; h < NHn; h++) {
      float w = 1.f;   // exp(0) for s > t (mask writes 0, not -inf)
      if (causal) {
        float dec = __expf(cst[h] - csr[h]);
        w = __expf(Lrow[h * NLEVn + lev] * dec);
      }
      unsigned short pb = f2bf(w);
      acc[h] += bf2f(pb);   // denominator consistent with rounded weights
      P[((size_t)h * Tn + t) * Tn + s] = pb;
    }
  }
  int lane = tid & 63;
#pragma unroll
  for (int h = 0; h < NHn; h++) {
    float v = acc[h];
    for (int o = 32; o > 0; o >>= 1) v += __shfl_down(v, o, 64);
    if (lane == 0) atomicAdd(&dsum[h], v);
  }
  __syncthreads();
  if (tid < NHn) denom[(size_t)tid * Tn + t] = dsum[tid];
}

// ---------------- transpose v: [b][t][h][d] -> [h][b][d][t] ----------------
__global__ void k_transpose(const unsigned short* __restrict__ vtmp, unsigned short* __restrict__ vt) {
  // grid: (Tn/64, Bn*NHn)
  __shared__ unsigned short tile[64][68];
  int bh = blockIdx.y;
  int b = bh >> 4, h = bh & 15;
  int t0 = blockIdx.x * 64;
  int tid = threadIdx.x;
#pragma unroll
  for (int j = 0; j < 4; j++) {
    int idx = j * 256 + tid;
    int r = idx >> 4, cg = idx & 15;
    ushort4 v = *(const ushort4*)&vtmp[((size_t)(b * Tn + t0 + r)) * En + h * HDn + cg * 4];
    *(ushort4*)&tile[r][cg * 4] = v;
  }
  __syncthreads();
#pragma unroll
  for (int j = 0; j < 4; j++) {
    int idx = j * 256 + tid;
    int d = idx >> 4, rg = idx & 15;
    ushort4 o;
    o.x = tile[rg * 4 + 0][d]; o.y = tile[rg * 4 + 1][d];
    o.z = tile[rg * 4 + 2][d]; o.w = tile[rg * 4 + 3][d];
    *(ushort4*)&vt[((size_t)((h * Bn + b) * HDn + d)) * Tn + t0 + rg * 4] = o;
  }
}

// ---------------- 128x128 bf16 MFMA GEMM, C = A(MxK,k-major) @ B(NxK,k-major)^T ----------------
// MODE 0: out bf16, +bias[col]        (v = x@Wv^T + bv)
// MODE 1: out fp32, +bias[col]        (y = o@Wo^T + bo)
// MODE 2: out bf16, scale 1/denom[h][row], scatter col=(b,d) -> [b][row][h*64+d]
template <int MODE>
__global__ __launch_bounds__(256)
void k_gemm(const unsigned short* __restrict__ A, const unsigned short* __restrict__ Bm,
            const float* __restrict__ aux, void* __restrict__ out, int M, int N, int K) {
  __shared__ unsigned short As[128 * 64];
  __shared__ unsigned short Bs[128 * 64];
  int tid = threadIdx.x;
  int wave = tid >> 6, lane = tid & 63;
  int wm = wave >> 1, wn = wave & 1;
  int bm = blockIdx.y * 128, bn = blockIdx.x * 128;
  int h = blockIdx.z;
  const unsigned short* Ap = A;
  const unsigned short* Bp = Bm;
  if (MODE == 2) {
    Ap += (size_t)h * Tn * Tn;           // P[h]
    Bp += (size_t)h * (Bn * HDn) * Tn;   // vt[h]
  }
  floatx4 zero4 = {0.f, 0.f, 0.f, 0.f};
  floatx4 acc[4][4];
#pragma unroll
  for (int i = 0; i < 4; i++)
#pragma unroll
    for (int j = 0; j < 4; j++) acc[i][j] = zero4;

  for (int k0 = 0; k0 < K; k0 += 64) {
    __syncthreads();
#pragma unroll
    for (int j = 0; j < 4; j++) {    // A tile: 128 rows x 64 k (16KB)
      int f = j * 256 + tid;
      int r = f >> 3, c = f & 7;
      int cg = c ^ (r & 7);          // XOR swizzle: breaks ds_read_b128 bank conflicts
      async16(&Ap[(size_t)(bm + r) * K + k0 + cg * 8], &As[f * 8]);
    }
#pragma unroll
    for (int j = 0; j < 4; j++) {    // B tile
      int f = j * 256 + tid;
      int r = f >> 3, c = f & 7;
      int cg = c ^ (r & 7);
      async16(&Bp[(size_t)(bn + r) * K + k0 + cg * 8], &Bs[f * 8]);
    }
    __syncthreads();                 // drains vmcnt for global_load_lds
#pragma unroll
    for (int kk = 0; kk < 2; kk++) {
      short8 af[4], bfr[4];
      int cgk = kk * 4 + (lane >> 4);
#pragma unroll
      for (int i = 0; i < 4; i++) {
        int m = wm * 64 + i * 16 + (lane & 15);
        af[i] = *(const short8*)&As[m * 64 + ((cgk ^ (m & 7)) * 8)];
        int n = wn * 64 + i * 16 + (lane & 15);
        bfr[i] = *(const short8*)&Bs[n * 64 + ((cgk ^ (n & 7)) * 8)];
      }
#pragma unroll
      for (int i = 0; i < 4; i++)
#pragma unroll
        for (int j = 0; j < 4; j++)
          acc[i][j] = __builtin_amdgcn_mfma_f32_16x16x32_bf16(af[i], bfr[j], acc[i][j], 0, 0, 0);
    }
  }
  // epilogue: C/D layout col=lane&15, row=(lane>>4)*4+reg (m89-verified)
#pragma unroll
  for (int i = 0; i < 4; i++) {
#pragma unroll
    for (int j = 0; j < 4; j++) {
#pragma unroll
      for (int r = 0; r < 4; r++) {
        int row = bm + wm * 64 + i * 16 + (lane >> 4) * 4 + r;
        int col = bn + wn * 64 + j * 16 + (lane & 15);
        float v = acc[i][j][r];
        if (MODE == 0) {
          v += aux[col];
          ((unsigned short*)out)[(size_t)row * N + col] = f2bf(v);
        } else if (MODE == 1) {
          v += aux[col];
          ((float*)out)[(size_t)row * N + col] = v;
        } else {
          float sc = 1.f / aux[(size_t)h * Tn + row];
          int b = col >> 6, d = col & 63;
          ((unsigned short*)out)[((size_t)(b * Tn + row)) * En + h * HDn + d] = f2bf(v * sc);
        }
      }
    }
  }
}

extern "C" void kernel_launch(void* const* d_in, const int* in_sizes, int n_in,
                              void* d_out, int out_size, void* d_ws, size_t ws_size,
                              hipStream_t stream) {
  const float* x      = (const float*)d_in[0];
  // d_in[1..4] = Wq, bq, Wk, bk — unused by the reference
  const float* Wv     = (const float*)d_in[5];
  const float* bv     = (const float*)d_in[6];
  const float* A_log  = (const float*)d_in[7];
  const float* A_bias = (const float*)d_in[8];
  const float* L      = (const float*)d_in[9];
  const float* Lb     = (const float*)d_in[10];
  const float* Wo     = (const float*)d_in[11];
  const float* bo     = (const float*)d_in[12];
  const int* levels   = (const int*)d_in[13];
  float* out = (float*)d_out;

  // workspace layout (bytes); Pw aliases xb+vtmp (both dead before k_weights)
  char* ws = (char*)d_ws;
  float* cs            = (float*)(ws + 0);                         // 128 KiB
  float* denom         = (float*)(ws + 131072);                    // 128 KiB
  unsigned short* Wvb  = (unsigned short*)(ws + 262144);           // 2 MiB
  unsigned short* Wob  = (unsigned short*)(ws + 2359296);          // 2 MiB
  unsigned short* xb   = (unsigned short*)(ws + 4456448);          // 64 MiB
  unsigned short* vtmp = (unsigned short*)(ws + 71565312);         // 64 MiB
  unsigned short* Pw   = (unsigned short*)(ws + 4456448);          // 128 MiB (aliases xb+vtmp)
  unsigned short* vt   = (unsigned short*)(ws + 138674176);        // 64 MiB
  unsigned short* outp = (unsigned short*)(ws + 205783040);        // 64 MiB
  if (ws_size < 272891904ULL) return;  // insufficient scratch -> fail loudly (zero output)

  int nx4 = Bn * Tn * En / 4;
  k_cvt<<<(nx4 + 255) / 256, 256, 0, stream>>>(x, xb, nx4);
  int nw4 = En * En / 4;
  k_cvt<<<(nw4 + 255) / 256, 256, 0, stream>>>(Wv, Wvb, nw4);
  k_cvt<<<(nw4 + 255) / 256, 256, 0, stream>>>(Wo, Wob, nw4);
  k_scan<<<NHn, 256, 0, stream>>>(A_log, A_bias, cs);

  dim3 g1(En / 128, (Bn * Tn) / 128, 1);
  k_gemm<0><<<g1, 256, 0, stream>>>(xb, Wvb, bv, vtmp, Bn * Tn, En, En);

  k_transpose<<<dim3(Tn / 64, Bn * NHn), 256, 0, stream>>>(vtmp, vt);

  k_weights<<<Tn, 256, 0, stream>>>(L, Lb, levels, cs, Pw, denom);

  dim3 g2((Bn * HDn) / 128, Tn / 128, NHn);
  k_gemm<2><<<g2, 256, 0, stream>>>(Pw, vt, denom, outp, Tn, Bn * HDn, Tn);

  dim3 g3(En / 128, (Bn * Tn) / 128, 1);
  k_gemm<1><<<g3, 256, 0, stream>>>(outp, Wob, bo, out, Bn * Tn, En, En);
}

// Round 2
// 698.925 us; speedup vs baseline: 1.0829x; 1.0829x over previous
//
#include <hip/hip_runtime.h>
#include <stdint.h>

static constexpr int Bn = 16, Tn = 2048, En = 1024, NHn = 16, HDn = 64, NLEVn = 12;

typedef __attribute__((ext_vector_type(8))) short short8;
typedef __attribute__((ext_vector_type(4))) float floatx4;

__device__ __forceinline__ unsigned short f2bf(float f) {
  unsigned int u = __float_as_uint(f);
  u += 0x7fffu + ((u >> 16) & 1u);
  return (unsigned short)(u >> 16);
}
__device__ __forceinline__ float bf2f(unsigned short s) {
  return __uint_as_float(((unsigned int)s) << 16);
}

__device__ __forceinline__ void async16(const unsigned short* g, unsigned short* l) {
  __builtin_amdgcn_global_load_lds(
      (const __attribute__((address_space(1))) unsigned int*)g,
      (__attribute__((address_space(3))) unsigned int*)l, 16, 0, 0);
}

// ---------------- fp32 -> bf16 convert ----------------
__global__ void k_cvt(const float* __restrict__ in, unsigned short* __restrict__ out, int n4) {
  int i = blockIdx.x * 256 + threadIdx.x;
  if (i < n4) {
    float4 v = ((const float4*)in)[i];
    ushort4 o;
    o.x = f2bf(v.x); o.y = f2bf(v.y); o.z = f2bf(v.z); o.w = f2bf(v.w);
    ((ushort4*)out)[i] = o;
  }
}

// ---------------- per-head prefix scan of log(sigmoid(A)) ----------------
__global__ void k_scan(const float* __restrict__ A_log, const float* __restrict__ A_bias,
                       float* __restrict__ cs) {
  int h = blockIdx.x;       // NH blocks
  int tid = threadIdx.x;    // 256 threads, 8 t each
  __shared__ float part[256];
  float loc[8];
  float run = 0.f;
#pragma unroll
  for (int j = 0; j < 8; j++) {
    int t = tid * 8 + j;
    float x = A_log[t * NHn + h] + A_bias[t * NHn + h];
    float ls = -log1pf(__expf(-x));   // log(sigmoid(x))
    run += ls;
    loc[j] = run;
  }
  part[tid] = run;
  __syncthreads();
  for (int d = 1; d < 256; d <<= 1) {
    float v = (tid >= d) ? part[tid - d] : 0.f;
    __syncthreads();
    part[tid] += v;
    __syncthreads();
  }
  float off = (tid > 0) ? part[tid - 1] : 0.f;
#pragma unroll
  for (int j = 0; j < 8; j++) cs[(tid * 8 + j) * NHn + h] = loc[j] + off;
}

// ---------------- unnormalized weights P[h][t][s] (bf16) + row sums ----------------
__global__ void k_weights(const float* __restrict__ L, const float* __restrict__ Lb,
                          const int* __restrict__ levels, const float* __restrict__ cs,
                          unsigned short* __restrict__ P, float* __restrict__ denom) {
  int t = blockIdx.x;       // T blocks
  int tid = threadIdx.x;    // 256
  __shared__ float Lrow[NHn * NLEVn];
  __shared__ float cst[NHn];
  __shared__ float dsum[NHn];
  if (tid < NHn * NLEVn) Lrow[tid] = L[t * NHn * NLEVn + tid] + Lb[t * NHn * NLEVn + tid];
  if (tid < NHn) { cst[tid] = cs[t * NHn + tid]; dsum[tid] = 0.f; }
  __syncthreads();
  float acc[NHn];
#pragma unroll
  for (int h = 0; h < NHn; h++) acc[h] = 0.f;
  for (int s = tid; s < Tn; s += 256) {
    int lev = levels[(size_t)t * Tn + s];
    bool causal = (s <= t);
    float csr[NHn];
    const float4* c4 = (const float4*)(cs + s * NHn);
#pragma unroll
    for (int q = 0; q < 4; q++) {
      float4 v = c4[q];
      csr[q * 4 + 0] = v.x; csr[q * 4 + 1] = v.y; csr[q * 4 + 2] = v.z; csr[q * 4 + 3] = v.w;
    }
#pragma unroll
    for (int h = 0; h < NHn; h++) {
      float w = 1.f;   // exp(0) for s > t (mask writes 0, not -inf)
      if (causal) {
        float dec = __expf(cst[h] - csr[h]);
        w = __expf(Lrow[h * NLEVn + lev] * dec);
      }
      unsigned short pb = f2bf(w);
      acc[h] += bf2f(pb);   // denominator consistent with rounded weights
      P[((size_t)h * Tn + t) * Tn + s] = pb;
    }
  }
  int lane = tid & 63;
#pragma unroll
  for (int h = 0; h < NHn; h++) {
    float v = acc[h];
    for (int o = 32; o > 0; o >>= 1) v += __shfl_down(v, o, 64);
    if (lane == 0) atomicAdd(&dsum[h], v);
  }
  __syncthreads();
  if (tid < NHn) denom[(size_t)tid * Tn + t] = dsum[tid];
}

// ---------------- transpose v: [b][t][h][d] -> [h][b][d][t] ----------------
__global__ void k_transpose(const unsigned short* __restrict__ vtmp, unsigned short* __restrict__ vt) {
  // grid: (Tn/64, Bn*NHn)
  __shared__ unsigned short tile[64][68];
  int bh = blockIdx.y;
  int b = bh >> 4, h = bh & 15;
  int t0 = blockIdx.x * 64;
  int tid = threadIdx.x;
#pragma unroll
  for (int j = 0; j < 4; j++) {
    int idx = j * 256 + tid;
    int r = idx >> 4, cg = idx & 15;
    ushort4 v = *(const ushort4*)&vtmp[((size_t)(b * Tn + t0 + r)) * En + h * HDn + cg * 4];
    *(ushort4*)&tile[r][cg * 4] = v;
  }
  __syncthreads();
#pragma unroll
  for (int j = 0; j < 4; j++) {
    int idx = j * 256 + tid;
    int d = idx >> 4, rg = idx & 15;
    ushort4 o;
    o.x = tile[rg * 4 + 0][d]; o.y = tile[rg * 4 + 1][d];
    o.z = tile[rg * 4 + 2][d]; o.w = tile[rg * 4 + 3][d];
    *(ushort4*)&vt[((size_t)((h * Bn + b) * HDn + d)) * Tn + t0 + rg * 4] = o;
  }
}

// ---------------- 128x128 bf16 MFMA GEMM, C = A(MxK,k-major) @ B(NxK,k-major)^T ----------------
// MODE 0: out bf16, +bias[col]        (v = x@Wv^T + bv)
// MODE 1: out fp32, +bias[col]        (y = o@Wo^T + bo)
// MODE 2: out bf16, scale 1/denom[h][row], scatter col=(b,d) -> [b][row][h*64+d]
//
// XCD-ownership swizzle: hardware assigns workgroups round-robin to the 8
// XCDs by linear dispatch id (flat % 8). We give each XCD a contiguous set
// of 32 A-strips; the 8 N-tile blocks sharing one strip run consecutively on
// ONE XCD, so strip re-reads hit that XCD's 4 MiB L2 instead of re-fetching
// HBM 8x (round-1 counters: FETCH 558 MB vs 66 MB ideal on the dense GEMMs).
// Requires gridDim.x == 8 and gridDim.y*gridDim.z == 256 (true for all 3 uses).
template <int MODE>
__global__ __launch_bounds__(256)
void k_gemm(const unsigned short* __restrict__ A, const unsigned short* __restrict__ Bm,
            const float* __restrict__ aux, void* __restrict__ out, int M, int N, int K) {
  __shared__ unsigned short As[128 * 64];
  __shared__ unsigned short Bs[128 * 64];
  int tid = threadIdx.x;
  int wave = tid >> 6, lane = tid & 63;
  int wm = wave >> 1, wn = wave & 1;

  int flat = (blockIdx.z * gridDim.y + blockIdx.y) * 8 + blockIdx.x;
  int xcd = flat & 7, slot = flat >> 3;
  int strip = xcd * 32 + (slot >> 3);   // 256 strips total, 32 per XCD
  int nt = slot & 7;
  int h, mt;
  if (MODE == 2) { h = strip >> 4; mt = strip & 15; }  // gridDim.y==16 m-tiles/head
  else           { h = 0;          mt = strip;      }  // gridDim.y==256 m-tiles
  int bm = mt * 128, bn = nt * 128;

  const unsigned short* Ap = A;
  const unsigned short* Bp = Bm;
  if (MODE == 2) {
    Ap += (size_t)h * Tn * Tn;           // P[h]
    Bp += (size_t)h * (Bn * HDn) * Tn;   // vt[h]
  }
  floatx4 zero4 = {0.f, 0.f, 0.f, 0.f};
  floatx4 acc[4][4];
#pragma unroll
  for (int i = 0; i < 4; i++)
#pragma unroll
    for (int j = 0; j < 4; j++) acc[i][j] = zero4;

  for (int k0 = 0; k0 < K; k0 += 64) {
    __syncthreads();
#pragma unroll
    for (int j = 0; j < 4; j++) {    // A tile: 128 rows x 64 k (16KB)
      int f = j * 256 + tid;
      int r = f >> 3, c = f & 7;
      int cg = c ^ (r & 7);          // XOR swizzle: breaks ds_read_b128 bank conflicts
      async16(&Ap[(size_t)(bm + r) * K + k0 + cg * 8], &As[f * 8]);
    }
#pragma unroll
    for (int j = 0; j < 4; j++) {    // B tile
      int f = j * 256 + tid;
      int r = f >> 3, c = f & 7;
      int cg = c ^ (r & 7);
      async16(&Bp[(size_t)(bn + r) * K + k0 + cg * 8], &Bs[f * 8]);
    }
    __syncthreads();                 // drains vmcnt for global_load_lds
#pragma unroll
    for (int kk = 0; kk < 2; kk++) {
      short8 af[4], bfr[4];
      int cgk = kk * 4 + (lane >> 4);
#pragma unroll
      for (int i = 0; i < 4; i++) {
        int m = wm * 64 + i * 16 + (lane & 15);
        af[i] = *(const short8*)&As[m * 64 + ((cgk ^ (m & 7)) * 8)];
        int n = wn * 64 + i * 16 + (lane & 15);
        bfr[i] = *(const short8*)&Bs[n * 64 + ((cgk ^ (n & 7)) * 8)];
      }
#pragma unroll
      for (int i = 0; i < 4; i++)
#pragma unroll
        for (int j = 0; j < 4; j++)
          acc[i][j] = __builtin_amdgcn_mfma_f32_16x16x32_bf16(af[i], bfr[j], acc[i][j], 0, 0, 0);
    }
  }
  // epilogue: C/D layout col=lane&15, row=(lane>>4)*4+reg (m89-verified)
#pragma unroll
  for (int i = 0; i < 4; i++) {
#pragma unroll
    for (int j = 0; j < 4; j++) {
#pragma unroll
      for (int r = 0; r < 4; r++) {
        int row = bm + wm * 64 + i * 16 + (lane >> 4) * 4 + r;
        int col = bn + wn * 64 + j * 16 + (lane & 15);
        float v = acc[i][j][r];
        if (MODE == 0) {
          v += aux[col];
          ((unsigned short*)out)[(size_t)row * N + col] = f2bf(v);
        } else if (MODE == 1) {
          v += aux[col];
          ((float*)out)[(size_t)row * N + col] = v;
        } else {
          float sc = 1.f / aux[(size_t)h * Tn + row];
          int b = col >> 6, d = col & 63;
          ((unsigned short*)out)[((size_t)(b * Tn + row)) * En + h * HDn + d] = f2bf(v * sc);
        }
      }
    }
  }
}

extern "C" void kernel_launch(void* const* d_in, const int* in_sizes, int n_in,
                              void* d_out, int out_size, void* d_ws, size_t ws_size,
                              hipStream_t stream) {
  const float* x      = (const float*)d_in[0];
  // d_in[1..4] = Wq, bq, Wk, bk — unused by the reference
  const float* Wv     = (const float*)d_in[5];
  const float* bv     = (const float*)d_in[6];
  const float* A_log  = (const float*)d_in[7];
  const float* A_bias = (const float*)d_in[8];
  const float* L      = (const float*)d_in[9];
  const float* Lb     = (const float*)d_in[10];
  const float* Wo     = (const float*)d_in[11];
  const float* bo     = (const float*)d_in[12];
  const int* levels   = (const int*)d_in[13];
  float* out = (float*)d_out;

  // workspace layout (bytes); Pw aliases xb+vtmp (both dead before k_weights)
  char* ws = (char*)d_ws;
  float* cs            = (float*)(ws + 0);                         // 128 KiB
  float* denom         = (float*)(ws + 131072);                    // 128 KiB
  unsigned short* Wvb  = (unsigned short*)(ws + 262144);           // 2 MiB
  unsigned short* Wob  = (unsigned short*)(ws + 2359296);          // 2 MiB
  unsigned short* xb   = (unsigned short*)(ws + 4456448);          // 64 MiB
  unsigned short* vtmp = (unsigned short*)(ws + 71565312);         // 64 MiB
  unsigned short* Pw   = (unsigned short*)(ws + 4456448);          // 128 MiB (aliases xb+vtmp)
  unsigned short* vt   = (unsigned short*)(ws + 138674176);        // 64 MiB
  unsigned short* outp = (unsigned short*)(ws + 205783040);        // 64 MiB
  if (ws_size < 272891904ULL) return;  // insufficient scratch -> fail loudly (zero output)

  int nx4 = Bn * Tn * En / 4;
  k_cvt<<<(nx4 + 255) / 256, 256, 0, stream>>>(x, xb, nx4);
  int nw4 = En * En / 4;
  k_cvt<<<(nw4 + 255) / 256, 256, 0, stream>>>(Wv, Wvb, nw4);
  k_cvt<<<(nw4 + 255) / 256, 256, 0, stream>>>(Wo, Wob, nw4);
  k_scan<<<NHn, 256, 0, stream>>>(A_log, A_bias, cs);

  dim3 g1(En / 128, (Bn * Tn) / 128, 1);
  k_gemm<0><<<g1, 256, 0, stream>>>(xb, Wvb, bv, vtmp, Bn * Tn, En, En);

  k_transpose<<<dim3(Tn / 64, Bn * NHn), 256, 0, stream>>>(vtmp, vt);

  k_weights<<<Tn, 256, 0, stream>>>(L, Lb, levels, cs, Pw, denom);

  dim3 g2((Bn * HDn) / 128, Tn / 128, NHn);
  k_gemm<2><<<g2, 256, 0, stream>>>(Pw, vt, denom, outp, Tn, Bn * HDn, Tn);

  dim3 g3(En / 128, (Bn * Tn) / 128, 1);
  k_gemm<1><<<g3, 256, 0, stream>>>(outp, Wob, bo, out, Bn * Tn, En, En);
}

// Round 3
// 677.048 us; speedup vs baseline: 1.1179x; 1.0323x over previous
//
#include <hip/hip_runtime.h>
#include <stdint.h>

static constexpr int Bn = 16, Tn = 2048, En = 1024, NHn = 16, HDn = 64, NLEVn = 12;

typedef __attribute__((ext_vector_type(8))) short short8;
typedef __attribute__((ext_vector_type(4))) float floatx4;

__device__ __forceinline__ unsigned short f2bf(float f) {
  unsigned int u = __float_as_uint(f);
  u += 0x7fffu + ((u >> 16) & 1u);
  return (unsigned short)(u >> 16);
}
__device__ __forceinline__ float bf2f(unsigned short s) {
  return __uint_as_float(((unsigned int)s) << 16);
}

__device__ __forceinline__ void async16(const unsigned short* g, unsigned short* l) {
  __builtin_amdgcn_global_load_lds(
      (const __attribute__((address_space(1))) unsigned int*)g,
      (__attribute__((address_space(3))) unsigned int*)l, 16, 0, 0);
}

// ---------------- fp32 -> bf16 convert ----------------
__global__ void k_cvt(const float* __restrict__ in, unsigned short* __restrict__ out, int n4) {
  int i = blockIdx.x * 256 + threadIdx.x;
  if (i < n4) {
    float4 v = ((const float4*)in)[i];
    ushort4 o;
    o.x = f2bf(v.x); o.y = f2bf(v.y); o.z = f2bf(v.z); o.w = f2bf(v.w);
    ((ushort4*)out)[i] = o;
  }
}

// ---------------- per-head prefix scan of log(sigmoid(A)) ----------------
__global__ void k_scan(const float* __restrict__ A_log, const float* __restrict__ A_bias,
                       float* __restrict__ cs) {
  int h = blockIdx.x;
  int tid = threadIdx.x;
  __shared__ float part[256];
  float loc[8];
  float run = 0.f;
#pragma unroll
  for (int j = 0; j < 8; j++) {
    int t = tid * 8 + j;
    float x = A_log[t * NHn + h] + A_bias[t * NHn + h];
    float ls = -log1pf(__expf(-x));
    run += ls;
    loc[j] = run;
  }
  part[tid] = run;
  __syncthreads();
  for (int d = 1; d < 256; d <<= 1) {
    float v = (tid >= d) ? part[tid - d] : 0.f;
    __syncthreads();
    part[tid] += v;
    __syncthreads();
  }
  float off = (tid > 0) ? part[tid - 1] : 0.f;
#pragma unroll
  for (int j = 0; j < 8; j++) cs[(tid * 8 + j) * NHn + h] = loc[j] + off;
}

// ---------------- unnormalized weights P[h][t][s] (bf16) + row sums ----------------
__global__ void k_weights(const float* __restrict__ L, const float* __restrict__ Lb,
                          const int* __restrict__ levels, const float* __restrict__ cs,
                          unsigned short* __restrict__ P, float* __restrict__ denom) {
  int t = blockIdx.x;
  int tid = threadIdx.x;
  __shared__ float Lrow[NHn * NLEVn];
  __shared__ float cst[NHn];
  __shared__ float dsum[NHn];
  if (tid < NHn * NLEVn) Lrow[tid] = L[t * NHn * NLEVn + tid] + Lb[t * NHn * NLEVn + tid];
  if (tid < NHn) { cst[tid] = cs[t * NHn + tid]; dsum[tid] = 0.f; }
  __syncthreads();
  float acc[NHn];
#pragma unroll
  for (int h = 0; h < NHn; h++) acc[h] = 0.f;
  for (int s = tid; s < Tn; s += 256) {
    int lev = levels[(size_t)t * Tn + s];
    bool causal = (s <= t);
    float csr[NHn];
    const float4* c4 = (const float4*)(cs + s * NHn);
#pragma unroll
    for (int q = 0; q < 4; q++) {
      float4 v = c4[q];
      csr[q * 4 + 0] = v.x; csr[q * 4 + 1] = v.y; csr[q * 4 + 2] = v.z; csr[q * 4 + 3] = v.w;
    }
#pragma unroll
    for (int h = 0; h < NHn; h++) {
      float w = 1.f;   // exp(0) for s > t (mask writes 0, not -inf)
      if (causal) {
        float dec = __expf(cst[h] - csr[h]);
        w = __expf(Lrow[h * NLEVn + lev] * dec);
      }
      unsigned short pb = f2bf(w);
      acc[h] += bf2f(pb);
      P[((size_t)h * Tn + t) * Tn + s] = pb;
    }
  }
  int lane = tid & 63;
#pragma unroll
  for (int h = 0; h < NHn; h++) {
    float v = acc[h];
    for (int o = 32; o > 0; o >>= 1) v += __shfl_down(v, o, 64);
    if (lane == 0) atomicAdd(&dsum[h], v);
  }
  __syncthreads();
  if (tid < NHn) denom[(size_t)tid * Tn + t] = dsum[tid];
}

// ================= GEMM 1: v = x@Wv^T + bv, 256x128 block, fused transpose =================
// A = xb (32768 x 1024 k-major), B = Wvb (1024 x 1024 k-major).
// Writes vt[h][b][d][t] directly (transpose fused via LDS).
// XCD-ownership swizzle: 128 strips of 256 rows, 16 strips/XCD.
__global__ __launch_bounds__(512)
void k_gemm_v(const unsigned short* __restrict__ A, const unsigned short* __restrict__ Bm,
              const float* __restrict__ bias, unsigned short* __restrict__ vt) {
  __shared__ unsigned short smem[24576];     // 48 KB: As(32K) | Bs(16K); epilogue reuses as Ct
  unsigned short* As = smem;                 // 256 x 64
  unsigned short* Bs = smem + 16384;         // 128 x 64
  const int K = 1024;
  int tid = threadIdx.x;
  int wave = tid >> 6, lane = tid & 63;
  int wm = wave >> 1, wn = wave & 1;         // 4 x 2 waves of 64x64 tiles

  int flat = blockIdx.y * 8 + blockIdx.x;    // gridDim.x == 8
  int xcd = flat & 7, slot = flat >> 3;      // slot 0..127
  int strip = xcd * 16 + (slot >> 3);        // 128 strips, 16 per XCD
  int nt = slot & 7;
  int bm = strip * 256, bn = nt * 128;

  floatx4 zero4 = {0.f, 0.f, 0.f, 0.f};
  floatx4 acc[4][4];
#pragma unroll
  for (int i = 0; i < 4; i++)
#pragma unroll
    for (int j = 0; j < 4; j++) acc[i][j] = zero4;

  for (int k0 = 0; k0 < K; k0 += 64) {
    __syncthreads();
#pragma unroll
    for (int j = 0; j < 4; j++) {            // A: 256 rows x 64 k (32KB)
      int f = j * 512 + tid;
      int r = f >> 3, c = f & 7;
      int cg = c ^ (r & 7);
      async16(&A[(size_t)(bm + r) * K + k0 + cg * 8], &As[f * 8]);
    }
#pragma unroll
    for (int j = 0; j < 2; j++) {            // B: 128 rows x 64 k (16KB)
      int f = j * 512 + tid;
      int r = f >> 3, c = f & 7;
      int cg = c ^ (r & 7);
      async16(&Bm[(size_t)(bn + r) * K + k0 + cg * 8], &Bs[f * 8]);
    }
    __syncthreads();
#pragma unroll
    for (int kk = 0; kk < 2; kk++) {
      short8 af[4], bfr[4];
      int cgk = kk * 4 + (lane >> 4);
#pragma unroll
      for (int i = 0; i < 4; i++) {
        int m = wm * 64 + i * 16 + (lane & 15);
        af[i] = *(const short8*)&As[m * 64 + ((cgk ^ (m & 7)) * 8)];
        int n = wn * 64 + i * 16 + (lane & 15);
        bfr[i] = *(const short8*)&Bs[n * 64 + ((cgk ^ (n & 7)) * 8)];
      }
#pragma unroll
      for (int i = 0; i < 4; i++)
#pragma unroll
        for (int j = 0; j < 4; j++)
          acc[i][j] = __builtin_amdgcn_mfma_f32_16x16x32_bf16(af[i], bfr[j], acc[i][j], 0, 0, 0);
    }
  }

  // ---- fused transpose epilogue: write vt[h][b][d][t] ----
  // Block rows are 256 consecutive t of one batch b; cols are 2 heads x 64 d.
  int b = bm >> 11, t0 = bm & 2047;
  unsigned short* Ct = smem;                 // 64 cols x (256+8) rows, 33.8 KB (fits 48 KB)
  const int S = 264;
#pragma unroll 1
  for (int pass = 0; pass < 2; pass++) {
    __syncthreads();
    if (wn == pass) {
#pragma unroll
      for (int i = 0; i < 4; i++) {
#pragma unroll
        for (int j = 0; j < 4; j++) {
          int colL = j * 16 + (lane & 15);
          float bia = bias[bn + pass * 64 + colL];
          int rowb = wm * 64 + i * 16 + (lane >> 4) * 4;
          ushort4 p;
          p.x = f2bf(acc[i][j][0] + bia);
          p.y = f2bf(acc[i][j][1] + bia);
          p.z = f2bf(acc[i][j][2] + bia);
          p.w = f2bf(acc[i][j][3] + bia);
          *(ushort4*)&Ct[colL * S + rowb] = p;   // rows contiguous: b64 write
        }
      }
    }
    __syncthreads();
    // copy out: 64 cols x 256 t, 512B contiguous runs along t
#pragma unroll
    for (int cc = 0; cc < 4; cc++) {
      int colL = wave * 8 + cc * 2 + (lane >> 5);
      int gc = bn + pass * 64 + colL;
      int h = gc >> 6, d = gc & 63;
      int tt = (lane & 31) * 8;
      short8 v = *(const short8*)&Ct[colL * S + tt];
      *(short8*)&vt[((size_t)((h * Bn + b) * HDn + d)) * Tn + t0 + tt] = v;
    }
  }
}

// ================= GEMM 2: attn @ v (per head), 128x128 block =================
// A = P[h] (2048x2048 k-major), B = vt[h] (1024x2048 k-major).
// out: scale 1/denom[h][row], scatter col=(b,d) -> outp[b][row][h*64+d] (bf16).
__global__ __launch_bounds__(256)
void k_gemm_attn(const unsigned short* __restrict__ P, const unsigned short* __restrict__ vt,
                 const float* __restrict__ denom, unsigned short* __restrict__ outp) {
  __shared__ unsigned short As[128 * 64];
  __shared__ unsigned short Bs[128 * 64];
  const int K = Tn;
  int tid = threadIdx.x;
  int wave = tid >> 6, lane = tid & 63;
  int wm = wave >> 1, wn = wave & 1;

  int flat = (blockIdx.z * gridDim.y + blockIdx.y) * 8 + blockIdx.x;
  int xcd = flat & 7, slot = flat >> 3;
  int strip = xcd * 32 + (slot >> 3);        // 256 strips = (h, mt)
  int nt = slot & 7;
  int h = strip >> 4, mt = strip & 15;
  int bm = mt * 128, bn = nt * 128;

  const unsigned short* Ap = P + (size_t)h * Tn * Tn;
  const unsigned short* Bp = vt + (size_t)h * (Bn * HDn) * Tn;

  floatx4 zero4 = {0.f, 0.f, 0.f, 0.f};
  floatx4 acc[4][4];
#pragma unroll
  for (int i = 0; i < 4; i++)
#pragma unroll
    for (int j = 0; j < 4; j++) acc[i][j] = zero4;

  for (int k0 = 0; k0 < K; k0 += 64) {
    __syncthreads();
#pragma unroll
    for (int j = 0; j < 4; j++) {
      int f = j * 256 + tid;
      int r = f >> 3, c = f & 7;
      int cg = c ^ (r & 7);
      async16(&Ap[(size_t)(bm + r) * K + k0 + cg * 8], &As[f * 8]);
    }
#pragma unroll
    for (int j = 0; j < 4; j++) {
      int f = j * 256 + tid;
      int r = f >> 3, c = f & 7;
      int cg = c ^ (r & 7);
      async16(&Bp[(size_t)(bn + r) * K + k0 + cg * 8], &Bs[f * 8]);
    }
    __syncthreads();
#pragma unroll
    for (int kk = 0; kk < 2; kk++) {
      short8 af[4], bfr[4];
      int cgk = kk * 4 + (lane >> 4);
#pragma unroll
      for (int i = 0; i < 4; i++) {
        int m = wm * 64 + i * 16 + (lane & 15);
        af[i] = *(const short8*)&As[m * 64 + ((cgk ^ (m & 7)) * 8)];
        int n = wn * 64 + i * 16 + (lane & 15);
        bfr[i] = *(const short8*)&Bs[n * 64 + ((cgk ^ (n & 7)) * 8)];
      }
#pragma unroll
      for (int i = 0; i < 4; i++)
#pragma unroll
        for (int j = 0; j < 4; j++)
          acc[i][j] = __builtin_amdgcn_mfma_f32_16x16x32_bf16(af[i], bfr[j], acc[i][j], 0, 0, 0);
    }
  }
#pragma unroll
  for (int i = 0; i < 4; i++) {
#pragma unroll
    for (int j = 0; j < 4; j++) {
#pragma unroll
      for (int r = 0; r < 4; r++) {
        int row = bm + wm * 64 + i * 16 + (lane >> 4) * 4 + r;
        int col = bn + wn * 64 + j * 16 + (lane & 15);
        float sc = 1.f / denom[(size_t)h * Tn + row];
        int b = col >> 6, d = col & 63;
        outp[((size_t)(b * Tn + row)) * En + h * HDn + d] = f2bf(acc[i][j][r] * sc);
      }
    }
  }
}

// ================= GEMM 3: out = o@Wo^T + bo, 128x128 block (round-2 control shape) =================
__global__ __launch_bounds__(256)
void k_gemm_out(const unsigned short* __restrict__ A, const unsigned short* __restrict__ Bm,
                const float* __restrict__ bias, float* __restrict__ out) {
  __shared__ unsigned short As[128 * 64];
  __shared__ unsigned short Bs[128 * 64];
  const int K = 1024, N = 1024;
  int tid = threadIdx.x;
  int wave = tid >> 6, lane = tid & 63;
  int wm = wave >> 1, wn = wave & 1;

  int flat = blockIdx.y * 8 + blockIdx.x;
  int xcd = flat & 7, slot = flat >> 3;
  int strip = xcd * 32 + (slot >> 3);        // 256 strips of 128 rows
  int nt = slot & 7;
  int bm = strip * 128, bn = nt * 128;

  floatx4 zero4 = {0.f, 0.f, 0.f, 0.f};
  floatx4 acc[4][4];
#pragma unroll
  for (int i = 0; i < 4; i++)
#pragma unroll
    for (int j = 0; j < 4; j++) acc[i][j] = zero4;

  for (int k0 = 0; k0 < K; k0 += 64) {
    __syncthreads();
#pragma unroll
    for (int j = 0; j < 4; j++) {
      int f = j * 256 + tid;
      int r = f >> 3, c = f & 7;
      int cg = c ^ (r & 7);
      async16(&A[(size_t)(bm + r) * K + k0 + cg * 8], &As[f * 8]);
    }
#pragma unroll
    for (int j = 0; j < 4; j++) {
      int f = j * 256 + tid;
      int r = f >> 3, c = f & 7;
      int cg = c ^ (r & 7);
      async16(&Bm[(size_t)(bn + r) * K + k0 + cg * 8], &Bs[f * 8]);
    }
    __syncthreads();
#pragma unroll
    for (int kk = 0; kk < 2; kk++) {
      short8 af[4], bfr[4];
      int cgk = kk * 4 + (lane >> 4);
#pragma unroll
      for (int i = 0; i < 4; i++) {
        int m = wm * 64 + i * 16 + (lane & 15);
        af[i] = *(const short8*)&As[m * 64 + ((cgk ^ (m & 7)) * 8)];
        int n = wn * 64 + i * 16 + (lane & 15);
        bfr[i] = *(const short8*)&Bs[n * 64 + ((cgk ^ (n & 7)) * 8)];
      }
#pragma unroll
      for (int i = 0; i < 4; i++)
#pragma unroll
        for (int j = 0; j < 4; j++)
          acc[i][j] = __builtin_amdgcn_mfma_f32_16x16x32_bf16(af[i], bfr[j], acc[i][j], 0, 0, 0);
    }
  }
#pragma unroll
  for (int i = 0; i < 4; i++) {
#pragma unroll
    for (int j = 0; j < 4; j++) {
#pragma unroll
      for (int r = 0; r < 4; r++) {
        int row = bm + wm * 64 + i * 16 + (lane >> 4) * 4 + r;
        int col = bn + wn * 64 + j * 16 + (lane & 15);
        out[(size_t)row * N + col] = acc[i][j][r] + bias[col];
      }
    }
  }
}

extern "C" void kernel_launch(void* const* d_in, const int* in_sizes, int n_in,
                              void* d_out, int out_size, void* d_ws, size_t ws_size,
                              hipStream_t stream) {
  const float* x      = (const float*)d_in[0];
  // d_in[1..4] = Wq, bq, Wk, bk — unused by the reference
  const float* Wv     = (const float*)d_in[5];
  const float* bv     = (const float*)d_in[6];
  const float* A_log  = (const float*)d_in[7];
  const float* A_bias = (const float*)d_in[8];
  const float* L      = (const float*)d_in[9];
  const float* Lb     = (const float*)d_in[10];
  const float* Wo     = (const float*)d_in[11];
  const float* bo     = (const float*)d_in[12];
  const int* levels   = (const int*)d_in[13];
  float* out = (float*)d_out;

  // workspace layout (bytes); Pw aliases xb (dead after k_gemm_v)
  char* ws = (char*)d_ws;
  float* cs            = (float*)(ws + 0);                  // 128 KiB
  float* denom         = (float*)(ws + 131072);             // 128 KiB
  unsigned short* Wvb  = (unsigned short*)(ws + 262144);    // 2 MiB
  unsigned short* Wob  = (unsigned short*)(ws + 2359296);   // 2 MiB
  unsigned short* xb   = (unsigned short*)(ws + 4456448);   // 64 MiB
  unsigned short* Pw   = (unsigned short*)(ws + 4456448);   // 128 MiB (aliases xb)
  unsigned short* vt   = (unsigned short*)(ws + 138674176); // 64 MiB
  unsigned short* outp = (unsigned short*)(ws + 205783040); // 64 MiB
  if (ws_size < 272891904ULL) return;

  int nx4 = Bn * Tn * En / 4;
  k_cvt<<<(nx4 + 255) / 256, 256, 0, stream>>>(x, xb, nx4);
  int nw4 = En * En / 4;
  k_cvt<<<(nw4 + 255) / 256, 256, 0, stream>>>(Wv, Wvb, nw4);
  k_cvt<<<(nw4 + 255) / 256, 256, 0, stream>>>(Wo, Wob, nw4);
  k_scan<<<NHn, 256, 0, stream>>>(A_log, A_bias, cs);

  k_gemm_v<<<dim3(8, 128), 512, 0, stream>>>(xb, Wvb, bv, vt);

  k_weights<<<Tn, 256, 0, stream>>>(L, Lb, levels, cs, Pw, denom);

  k_gemm_attn<<<dim3(8, 16, 16), 256, 0, stream>>>(Pw, vt, denom, outp);

  k_gemm_out<<<dim3(8, 256), 256, 0, stream>>>(outp, Wob, bo, out);
}